// Round 9
// baseline (202.655 us; speedup 1.0000x reference)
//
#include <hip/hip_runtime.h>

typedef unsigned short ushort_t;
typedef __attribute__((ext_vector_type(8))) short short8;
typedef __attribute__((ext_vector_type(4))) float f32x4;
typedef __attribute__((ext_vector_type(16))) float f32x16;
typedef __attribute__((ext_vector_type(4))) float float4v;
typedef __attribute__((ext_vector_type(4))) unsigned short ushortx4;
typedef __attribute__((ext_vector_type(4))) unsigned int uint4v;

#define AS1 __attribute__((address_space(1)))
#define AS3 __attribute__((address_space(3)))

#define B_ 4
#define N_ 2048
#define C_ 1024
#define H_ 16
#define HD_ 64
#define M_TOT 8192
#define N3_ 3072

// q scale: 1/sqrt(64) * log2(e) so softmax runs in exp2 domain
#define QSCALE 0.18033688011112042f

__device__ __forceinline__ unsigned short f2bf(float f) {
    unsigned int u = __float_as_uint(f);
    u += 0x7fffu + ((u >> 16) & 1u);
    return (unsigned short)(u >> 16);
}

__global__ __launch_bounds__(256) void cast_f32_bf16(const float* __restrict__ in,
                                                     ushort_t* __restrict__ out, int n4) {
    int i = blockIdx.x * blockDim.x + threadIdx.x;
    int stride = gridDim.x * blockDim.x;
    for (; i < n4; i += stride) {
        float4v v = ((const float4v*)in)[i];
        ushortx4 o;
        o[0] = f2bf(v[0]); o[1] = f2bf(v[1]); o[2] = f2bf(v[2]); o[3] = f2bf(v[3]);
        ((ushortx4*)out)[i] = o;
    }
}

// Fragment-major layouts for attention (lane = 64-lane wave index, 32x32x16 MFMA):
//  Q/K element (bh, n, hd): blk=n>>5, ks=hd>>4, lane=(n&31)+32*((hd>>3)&1), e=hd&7
//    addr = ((bh*64+blk)*4+ks)*512 + lane*8 + e
//  V element (bh, kv, d): t=kv>>5, dt=d>>5, kb=(kv>>4)&1, lane=(d&31)+32*((kv>>3)&1), e=kv&7
//    addr = (((bh*64+t)*2+dt)*2+kb)*512 + lane*8 + e   (= (t*4 + dt*2+kb)*512 + ...)

// C = A @ B^T, A [M][K] bf16 row-major, B [N][K] bf16 row-major. 128x128 tile, BK=32.
// EPI 0: scatter qkv into fragment-major q (*QSCALE), k, v
// EPI 1: out f32 [M][1024] += bias
template <int EPI>
__global__ __launch_bounds__(256) void gemm_bt(const ushort_t* __restrict__ A,
                                               const ushort_t* __restrict__ Bw,
                                               ushort_t* __restrict__ o0,
                                               ushort_t* __restrict__ o1,
                                               ushort_t* __restrict__ o2,
                                               float* __restrict__ outf,
                                               const float* __restrict__ bias, int K) {
    __shared__ ushort_t As[2][128 * 32];
    __shared__ ushort_t Bs[2][128 * 32];
    const int tid = threadIdx.x;
    const int lane = tid & 63;
    const int wid = tid >> 6;
    const int l15 = lane & 15, lg = lane >> 4;
    const int wr = wid >> 1, wc = wid & 1;
    const int m0 = blockIdx.y * 128, n0 = blockIdx.x * 128;

    f32x4 acc[4][4] = {};

    auto stage = [&](int buf, int k0) {
        int row = tid >> 2;
        int ko = (tid & 3) * 8;
        const ushort_t* a0 = A + (size_t)(m0 + row) * K + k0 + ko;
        const ushort_t* b0 = Bw + (size_t)(n0 + row) * K + k0 + ko;
        char* la = (char*)(&As[buf][0]) + (tid & 192) * 16;  // wave-uniform base
        char* lb = (char*)(&Bs[buf][0]) + (tid & 192) * 16;
        __builtin_amdgcn_global_load_lds((const AS1 void*)a0, (AS3 void*)la, 16, 0, 0);
        __builtin_amdgcn_global_load_lds((const AS1 void*)(a0 + (size_t)64 * K),
                                         (AS3 void*)(la + 4096), 16, 0, 0);
        __builtin_amdgcn_global_load_lds((const AS1 void*)b0, (AS3 void*)lb, 16, 0, 0);
        __builtin_amdgcn_global_load_lds((const AS1 void*)(b0 + (size_t)64 * K),
                                         (AS3 void*)(lb + 4096), 16, 0, 0);
    };

    stage(0, 0);
    __syncthreads();
    const int NKI = K >> 5;
    for (int kt = 0; kt < NKI; ++kt) {
        const int cur = kt & 1;
        if (kt + 1 < NKI) stage(cur ^ 1, (kt + 1) << 5);
        short8 af[4], bf[4];
#pragma unroll
        for (int mi = 0; mi < 4; ++mi)
            af[mi] = *(const short8*)(&As[cur][(wr * 64 + mi * 16 + l15) * 32 + lg * 8]);
#pragma unroll
        for (int ni = 0; ni < 4; ++ni)
            bf[ni] = *(const short8*)(&Bs[cur][(wc * 64 + ni * 16 + l15) * 32 + lg * 8]);
#pragma unroll
        for (int mi = 0; mi < 4; ++mi)
#pragma unroll
            for (int ni = 0; ni < 4; ++ni)
                acc[mi][ni] = __builtin_amdgcn_mfma_f32_16x16x32_bf16(af[mi], bf[ni],
                                                                      acc[mi][ni], 0, 0, 0);
        __syncthreads();
    }

    if (EPI == 0) {
        const int sel = blockIdx.x >> 3;  // 0=q 1=k 2=v, uniform per block
        const int cb = (blockIdx.x & 7) * 128 + wc * 64;
#pragma unroll
        for (int mi = 0; mi < 4; ++mi) {
            const int r0 = m0 + wr * 64 + mi * 16 + lg * 4;
            const int b = r0 >> 11, n = r0 & 2047;
            const int blk = n >> 5, nlo = n & 31;
#pragma unroll
            for (int ni = 0; ni < 4; ++ni) {
                const int c = cb + ni * 16 + l15;
                const int h = c >> 6, hd = c & 63;
                const int bh = b * H_ + h;
                f32x4 a = acc[mi][ni];
                if (sel == 2) {
                    // V fragment-major, 4 consecutive kv at fixed d -> 8B vector store
                    size_t base = (((size_t)(bh * 64 + blk) * 2 + (hd >> 5)) * 2 +
                                   ((n >> 4) & 1)) * 512 +
                                  ((hd & 31) + ((n >> 3) & 1) * 32) * 8 + (n & 7);
                    ushortx4 pk;
#pragma unroll
                    for (int j = 0; j < 4; ++j) pk[j] = f2bf(a[j]);
                    *(ushortx4*)(&o2[base]) = pk;
                } else {
                    // Q/K fragment-major, 4 consecutive n at fixed hd -> lane-stride 16B
                    size_t base = ((size_t)(bh * 64 + blk) * 4 + (hd >> 4)) * 512 +
                                  (nlo + ((hd >> 3) & 1) * 32) * 8 + (hd & 7);
                    if (sel == 0) {
#pragma unroll
                        for (int j = 0; j < 4; ++j) o0[base + j * 8] = f2bf(a[j] * QSCALE);
                    } else {
#pragma unroll
                        for (int j = 0; j < 4; ++j) o1[base + j * 8] = f2bf(a[j]);
                    }
                }
            }
        }
    } else {
#pragma unroll
        for (int ni = 0; ni < 4; ++ni) {
            const int c = n0 + wc * 64 + ni * 16 + l15;
            const float bv = bias[c];
#pragma unroll
            for (int mi = 0; mi < 4; ++mi) {
                const int r0 = m0 + wr * 64 + mi * 16 + lg * 4;
                f32x4 a = acc[mi][ni];
#pragma unroll
                for (int j = 0; j < 4; ++j)
                    outf[(size_t)(r0 + j) * C_ + c] = a[j] + bv;
            }
        }
    }
}

// Flash attention v9: v8's LDS-staged structure (K/V staged once per block via
// global_load_lds, double-buffered, one barrier per tile; fixed-base softmax;
// ones-MFMA row-sum; cvt_pk+permlane P redistribution) but 1024 blocks x
// 4 waves x 32 q-rows: v8 was GRID-limited to 2 blocks/CU (VGPR was only 100)
// and every pipe sat at 40-50% -- latency-bound at 2 waves/SIMD. Halving
// per-wave q-state drops VGPR to ~85 -> 4 blocks/CU resident, 4 waves/SIMD,
// and cross-block waves share no barriers.
__global__ __launch_bounds__(256, 2) void attn_fwd(const ushort_t* __restrict__ Qf,
                                                   const ushort_t* __restrict__ Kf,
                                                   const ushort_t* __restrict__ Vf,
                                                   ushort_t* __restrict__ Ov) {
    __shared__ ushort_t kvlds[2][8 * 512];  // [buf][K ks0..3 | V f0..3] x 1KB chunks
    const int tid = threadIdx.x;
    const int lane = tid & 63;
    const int wid = tid >> 6;
    const int lc = lane & 31, lh = lane >> 5;

    const int wg = blockIdx.x;          // 1024 blocks
    const int xcd = wg & 7, slot = wg >> 3;
    const int bh = xcd * 8 + (slot >> 4);
    const int qt = slot & 15;           // 16 q-chunks of 128 rows per bh

    const ushort_t* qpb = Qf + (size_t)bh * N_ * HD_;
    const ushort_t* kpb = Kf + (size_t)bh * N_ * HD_;
    const ushort_t* vpb = Vf + (size_t)bh * N_ * HD_;

    const int qblk = qt * 4 + wid;      // this wave's q-block (32 rows)

    short8 qf[4];
#pragma unroll
    for (int ks = 0; ks < 4; ++ks)
        qf[ks] = *(const short8*)(qpb + ((size_t)qblk * 4 + ks) * 512 + lane * 8);

    f32x16 oacc[2] = {};
    f32x16 ssum = {};

    uint4v ow;
    ow[0] = 0x3F803F80u; ow[1] = 0x3F803F80u; ow[2] = 0x3F803F80u; ow[3] = 0x3F803F80u;
    const short8 onesf = __builtin_bit_cast(short8, ow);

    // stage K/V tile t into kvlds[buf]: 8 x 1KB chunks, 2 per wave.
    // wid 0: K ks{0,1}; wid 1: K ks{2,3}; wid 2: V f{0,1}; wid 3: V f{2,3}.
    auto stage = [&](int buf, int t) {
        const ushort_t* bsrc = (wid < 2) ? kpb : vpb;
        const int coff = (wid & 1) * 2;
        const ushort_t* s0 = bsrc + ((size_t)t * 4 + coff) * 512 + lane * 8;
        ushort_t* d0 = &kvlds[buf][(wid * 2) * 512];
        __builtin_amdgcn_global_load_lds((const AS1 void*)s0, (AS3 void*)d0, 16, 0, 0);
        __builtin_amdgcn_global_load_lds((const AS1 void*)(s0 + 512), (AS3 void*)(d0 + 512),
                                         16, 0, 0);
    };

    stage(0, 0);
    __syncthreads();

    for (int t = 0; t < 64; ++t) {
        const int cur = t & 1;
        if (t < 63) stage(cur ^ 1, t + 1);

        short8 kf[4], vf[4];
#pragma unroll
        for (int ks = 0; ks < 4; ++ks)
            kf[ks] = *(const short8*)(&kvlds[cur][ks * 512 + lane * 8]);
#pragma unroll
        for (int f = 0; f < 4; ++f)
            vf[f] = *(const short8*)(&kvlds[cur][(4 + f) * 512 + lane * 8]);

        // QK^T: S^T[kv][q]
        f32x16 sacc = {};
        __builtin_amdgcn_s_setprio(1);
#pragma unroll
        for (int ks = 0; ks < 4; ++ks)
            sacc = __builtin_amdgcn_mfma_f32_32x32x16_bf16(kf[ks], qf[ks], sacc, 0, 0, 0);
        __builtin_amdgcn_s_setprio(0);

        // fixed-base softmax: P = exp2(s) (q pre-scaled by QSCALE)
        float p[16];
#pragma unroll
        for (int r = 0; r < 16; ++r) p[r] = __builtin_amdgcn_exp2f(sacc[r]);

        // pack to bf16 pairs: pk[r1][c] holds kv pair (8r1+4lh+2c, +1) at col lc
        unsigned pk[4][2];
#pragma unroll
        for (int r1 = 0; r1 < 4; ++r1)
#pragma unroll
            for (int c = 0; c < 2; ++c)
                asm("v_cvt_pk_bf16_f32 %0, %1, %2"
                    : "=v"(pk[r1][c])
                    : "v"(p[4 * r1 + 2 * c]), "v"(p[4 * r1 + 2 * c + 1]));

        // permlane32_swap -> PV B-fragment entirely in registers
        short8 pb[2];
#pragma unroll
        for (int kb = 0; kb < 2; ++kb) {
            unsigned a0 = pk[2 * kb][0], b0 = pk[2 * kb + 1][0];
            unsigned a1 = pk[2 * kb][1], b1 = pk[2 * kb + 1][1];
            asm("v_permlane32_swap_b32 %0, %1" : "+v"(a0), "+v"(b0));
            asm("v_permlane32_swap_b32 %0, %1" : "+v"(a1), "+v"(b1));
            uint4v w;
            w[0] = a0; w[1] = a1; w[2] = b0; w[3] = b1;
            pb[kb] = __builtin_bit_cast(short8, w);
        }

        // row-sum of P on the MFMA pipe + PV: O^T[d][q] += V^T . P^T
        __builtin_amdgcn_s_setprio(1);
        ssum = __builtin_amdgcn_mfma_f32_32x32x16_bf16(onesf, pb[0], ssum, 0, 0, 0);
        ssum = __builtin_amdgcn_mfma_f32_32x32x16_bf16(onesf, pb[1], ssum, 0, 0, 0);
#pragma unroll
        for (int dt = 0; dt < 2; ++dt)
#pragma unroll
            for (int kb = 0; kb < 2; ++kb)
                oacc[dt] = __builtin_amdgcn_mfma_f32_32x32x16_bf16(vf[dt * 2 + kb], pb[kb],
                                                                   oacc[dt], 0, 0, 0);
        __builtin_amdgcn_s_setprio(0);
        __syncthreads();
    }

    const float inv = 1.f / ssum[0];
    const int b = bh >> 4, h = bh & 15;
    const int qg = qblk * 32 + lc;
    ushort_t* orow = Ov + (size_t)(b * N_ + qg) * C_ + h * HD_;
#pragma unroll
    for (int dt = 0; dt < 2; ++dt)
#pragma unroll
        for (int r1 = 0; r1 < 4; ++r1) {
            ushortx4 pkv;
#pragma unroll
            for (int r0 = 0; r0 < 4; ++r0) pkv[r0] = f2bf(oacc[dt][4 * r1 + r0] * inv);
            *(ushortx4*)(orow + dt * 32 + r1 * 8 + lh * 4) = pkv;
        }
}

extern "C" void kernel_launch(void* const* d_in, const int* in_sizes, int n_in,
                              void* d_out, int out_size, void* d_ws, size_t ws_size,
                              hipStream_t stream) {
    const float* x = (const float*)d_in[0];
    const float* wqkv = (const float*)d_in[1];
    const float* wout = (const float*)d_in[2];
    const float* bout = (const float*)d_in[3];
    float* out = (float*)d_out;

    ushort_t* ws = (ushort_t*)d_ws;
    const size_t XN = (size_t)M_TOT * C_;       // 8388608
    const size_t WQN = (size_t)N3_ * C_;        // 3145728
    const size_t WON = (size_t)C_ * C_;         // 1048576
    ushort_t* xbf = ws;                         // also reused as vhat after gemm1
    ushort_t* wqkvb = xbf + XN;
    ushort_t* woutb = wqkvb + WQN;
    ushort_t* karr = woutb + WON;
    ushort_t* varr = karr + XN;
    ushort_t* qarr = varr + XN;
    ushort_t* vhat = xbf;  // alias: x_bf dead after gemm1

    cast_f32_bf16<<<2048, 256, 0, stream>>>(x, xbf, (int)(XN / 4));
    cast_f32_bf16<<<1024, 256, 0, stream>>>(wqkv, wqkvb, (int)(WQN / 4));
    cast_f32_bf16<<<512, 256, 0, stream>>>(wout, woutb, (int)(WON / 4));

    gemm_bt<0><<<dim3(24, 64), 256, 0, stream>>>(xbf, wqkvb, qarr, karr, varr,
                                                 nullptr, nullptr, C_);
    attn_fwd<<<1024, 256, 0, stream>>>(qarr, karr, varr, vhat);
    gemm_bt<1><<<dim3(8, 64), 256, 0, stream>>>(vhat, woutb, nullptr, nullptr, nullptr,
                                                out, bout, C_);
}

// Round 10
// 193.968 us; speedup vs baseline: 1.0448x; 1.0448x over previous
//
#include <hip/hip_runtime.h>

typedef unsigned short ushort_t;
typedef __attribute__((ext_vector_type(8))) short short8;
typedef __attribute__((ext_vector_type(4))) float f32x4;
typedef __attribute__((ext_vector_type(16))) float f32x16;
typedef __attribute__((ext_vector_type(4))) float float4v;
typedef __attribute__((ext_vector_type(4))) unsigned short ushortx4;
typedef __attribute__((ext_vector_type(4))) unsigned int uint4v;

#define AS1 __attribute__((address_space(1)))
#define AS3 __attribute__((address_space(3)))

#define B_ 4
#define N_ 2048
#define C_ 1024
#define H_ 16
#define HD_ 64
#define M_TOT 8192
#define N3_ 3072

// q scale: 1/sqrt(64) * log2(e) so softmax runs in exp2 domain
#define QSCALE 0.18033688011112042f

__device__ __forceinline__ unsigned short f2bf(float f) {
    unsigned int u = __float_as_uint(f);
    u += 0x7fffu + ((u >> 16) & 1u);
    return (unsigned short)(u >> 16);
}

__global__ __launch_bounds__(256) void cast_f32_bf16(const float* __restrict__ in,
                                                     ushort_t* __restrict__ out, int n4) {
    int i = blockIdx.x * blockDim.x + threadIdx.x;
    int stride = gridDim.x * blockDim.x;
    for (; i < n4; i += stride) {
        float4v v = ((const float4v*)in)[i];
        ushortx4 o;
        o[0] = f2bf(v[0]); o[1] = f2bf(v[1]); o[2] = f2bf(v[2]); o[3] = f2bf(v[3]);
        ((ushortx4*)out)[i] = o;
    }
}

// Fragment-major layouts for attention (lane = 64-lane wave index, 32x32x16 MFMA):
//  Q/K element (bh, n, hd): blk=n>>5, ks=hd>>4, lane=(n&31)+32*((hd>>3)&1), e=hd&7
//    addr = ((bh*64+blk)*4+ks)*512 + lane*8 + e
//  V element (bh, kv, d): t=kv>>5, dt=d>>5, kb=(kv>>4)&1, lane=(d&31)+32*((kv>>3)&1), e=kv&7
//    addr = (((bh*64+t)*2+dt)*2+kb)*512 + lane*8 + e

// C = A @ B^T, A [M][K] bf16 row-major, B [N][K] bf16 row-major. 128x128 tile, BK=32.
// EPI 0: scatter qkv into fragment-major q (*QSCALE), k, v
// EPI 1: out f32 [M][1024] += bias
template <int EPI>
__global__ __launch_bounds__(256) void gemm_bt(const ushort_t* __restrict__ A,
                                               const ushort_t* __restrict__ Bw,
                                               ushort_t* __restrict__ o0,
                                               ushort_t* __restrict__ o1,
                                               ushort_t* __restrict__ o2,
                                               float* __restrict__ outf,
                                               const float* __restrict__ bias, int K) {
    __shared__ ushort_t As[2][128 * 32];
    __shared__ ushort_t Bs[2][128 * 32];
    const int tid = threadIdx.x;
    const int lane = tid & 63;
    const int wid = tid >> 6;
    const int l15 = lane & 15, lg = lane >> 4;
    const int wr = wid >> 1, wc = wid & 1;
    const int m0 = blockIdx.y * 128, n0 = blockIdx.x * 128;

    f32x4 acc[4][4] = {};

    auto stage = [&](int buf, int k0) {
        int row = tid >> 2;
        int ko = (tid & 3) * 8;
        const ushort_t* a0 = A + (size_t)(m0 + row) * K + k0 + ko;
        const ushort_t* b0 = Bw + (size_t)(n0 + row) * K + k0 + ko;
        char* la = (char*)(&As[buf][0]) + (tid & 192) * 16;  // wave-uniform base
        char* lb = (char*)(&Bs[buf][0]) + (tid & 192) * 16;
        __builtin_amdgcn_global_load_lds((const AS1 void*)a0, (AS3 void*)la, 16, 0, 0);
        __builtin_amdgcn_global_load_lds((const AS1 void*)(a0 + (size_t)64 * K),
                                         (AS3 void*)(la + 4096), 16, 0, 0);
        __builtin_amdgcn_global_load_lds((const AS1 void*)b0, (AS3 void*)lb, 16, 0, 0);
        __builtin_amdgcn_global_load_lds((const AS1 void*)(b0 + (size_t)64 * K),
                                         (AS3 void*)(lb + 4096), 16, 0, 0);
    };

    stage(0, 0);
    __syncthreads();
    const int NKI = K >> 5;
    for (int kt = 0; kt < NKI; ++kt) {
        const int cur = kt & 1;
        if (kt + 1 < NKI) stage(cur ^ 1, (kt + 1) << 5);
        short8 af[4], bf[4];
#pragma unroll
        for (int mi = 0; mi < 4; ++mi)
            af[mi] = *(const short8*)(&As[cur][(wr * 64 + mi * 16 + l15) * 32 + lg * 8]);
#pragma unroll
        for (int ni = 0; ni < 4; ++ni)
            bf[ni] = *(const short8*)(&Bs[cur][(wc * 64 + ni * 16 + l15) * 32 + lg * 8]);
#pragma unroll
        for (int mi = 0; mi < 4; ++mi)
#pragma unroll
            for (int ni = 0; ni < 4; ++ni)
                acc[mi][ni] = __builtin_amdgcn_mfma_f32_16x16x32_bf16(af[mi], bf[ni],
                                                                      acc[mi][ni], 0, 0, 0);
        __syncthreads();
    }

    if (EPI == 0) {
        const int sel = blockIdx.x >> 3;  // 0=q 1=k 2=v, uniform per block
        const int cb = (blockIdx.x & 7) * 128 + wc * 64;
#pragma unroll
        for (int mi = 0; mi < 4; ++mi) {
            const int r0 = m0 + wr * 64 + mi * 16 + lg * 4;
            const int b = r0 >> 11, n = r0 & 2047;
            const int blk = n >> 5, nlo = n & 31;
#pragma unroll
            for (int ni = 0; ni < 4; ++ni) {
                const int c = cb + ni * 16 + l15;
                const int h = c >> 6, hd = c & 63;
                const int bh = b * H_ + h;
                f32x4 a = acc[mi][ni];
                if (sel == 2) {
                    // V fragment-major, 4 consecutive kv at fixed d -> 8B vector store
                    size_t base = (((size_t)(bh * 64 + blk) * 2 + (hd >> 5)) * 2 +
                                   ((n >> 4) & 1)) * 512 +
                                  ((hd & 31) + ((n >> 3) & 1) * 32) * 8 + (n & 7);
                    ushortx4 pk;
#pragma unroll
                    for (int j = 0; j < 4; ++j) pk[j] = f2bf(a[j]);
                    *(ushortx4*)(&o2[base]) = pk;
                } else {
                    // Q/K fragment-major, 4 consecutive n at fixed hd -> lane-stride 16B
                    size_t base = ((size_t)(bh * 64 + blk) * 4 + (hd >> 4)) * 512 +
                                  (nlo + ((hd >> 3) & 1) * 32) * 8 + (hd & 7);
                    if (sel == 0) {
#pragma unroll
                        for (int j = 0; j < 4; ++j) o0[base + j * 8] = f2bf(a[j] * QSCALE);
                    } else {
#pragma unroll
                        for (int j = 0; j < 4; ++j) o1[base + j * 8] = f2bf(a[j]);
                    }
                }
            }
        }
    } else {
#pragma unroll
        for (int ni = 0; ni < 4; ++ni) {
            const int c = n0 + wc * 64 + ni * 16 + l15;
            const float bv = bias[c];
#pragma unroll
            for (int mi = 0; mi < 4; ++mi) {
                const int r0 = m0 + wr * 64 + mi * 16 + lg * 4;
                f32x4 a = acc[mi][ni];
#pragma unroll
                for (int j = 0; j < 4; ++j)
                    outf[(size_t)(r0 + j) * C_ + c] = a[j] + bv;
            }
        }
    }
}

// Flash attention v10: exact round-4 structure (best measured: fragment-major
// coalesced register-direct loads, 512 blocks x 4 waves x 64 q-rows, K/V
// register-pipelined one tile ahead, fixed-base softmax, cvt_pk+permlane P
// redistribution) + ONE-TIME PER-WAVE PHASE STAGGER: evidence from v4-v9 says
// wall ~= sum of MFMA+VALU+LDS pipe demands (no cross-wave pipe overlap) because
// all waves run the same symmetric loop in phase lockstep. s_sleep of
// 0/192/384/576cy keyed by (wid+block)&3 spreads co-resident waves across the
// ~750cy iteration so one wave's exp2/pack overlaps another's MFMA cluster.
__global__ __launch_bounds__(256, 2) void attn_fwd(const ushort_t* __restrict__ Qf,
                                                   const ushort_t* __restrict__ Kf,
                                                   const ushort_t* __restrict__ Vf,
                                                   ushort_t* __restrict__ Ov) {
    const int tid = threadIdx.x;
    const int lane = tid & 63;
    const int wid = tid >> 6;
    const int lc = lane & 31, lh = lane >> 5;

    const int wg = blockIdx.x;          // 512 blocks
    const int xcd = wg & 7, slot = wg >> 3;
    const int bh = xcd * 8 + (slot >> 3);
    const int qt = slot & 7;            // 8 q-chunks of 256 rows per bh

    const ushort_t* qpb = Qf + (size_t)bh * N_ * HD_;
    const ushort_t* kpb = Kf + (size_t)bh * N_ * HD_;
    const ushort_t* vpb = Vf + (size_t)bh * N_ * HD_;

    const int qblk0 = qt * 8 + wid * 2;  // first of this wave's 2 q-blocks (32 rows each)

    short8 qf[2][4];
#pragma unroll
    for (int qc = 0; qc < 2; ++qc)
#pragma unroll
        for (int ks = 0; ks < 4; ++ks)
            qf[qc][ks] = *(const short8*)(qpb + ((size_t)(qblk0 + qc) * 4 + ks) * 512 +
                                          lane * 8);

    // phase stagger: one-time offset so co-resident waves decorrelate phases
    {
        const int ph = (wid + (wg & 3)) & 3;
        if (ph == 1) __builtin_amdgcn_s_sleep(3);
        else if (ph == 2) __builtin_amdgcn_s_sleep(6);
        else if (ph == 3) __builtin_amdgcn_s_sleep(9);
    }

    f32x16 oacc[2][2] = {};
    float srun[2] = {0.f, 0.f};

    short8 kfA[4], kfB[4], vfA[4], vfB[4];
#pragma unroll
    for (int ks = 0; ks < 4; ++ks)
        kfA[ks] = *(const short8*)(kpb + (size_t)ks * 512 + lane * 8);
#pragma unroll
    for (int dt = 0; dt < 2; ++dt)
#pragma unroll
        for (int kb = 0; kb < 2; ++kb)
            vfA[dt * 2 + kb] = *(const short8*)(vpb + ((size_t)dt * 2 + kb) * 512 + lane * 8);

    auto iter = [&](short8(&kfu)[4], short8(&kfp)[4], short8(&vfu)[4], short8(&vfp)[4],
                    int t) {
        // QK^T both q-cols: S^T[kv][q]
        f32x16 sacc[2] = {};
        __builtin_amdgcn_s_setprio(1);
#pragma unroll
        for (int ks = 0; ks < 4; ++ks)
#pragma unroll
            for (int qc = 0; qc < 2; ++qc)
                sacc[qc] = __builtin_amdgcn_mfma_f32_32x32x16_bf16(kfu[ks], qf[qc][ks],
                                                                   sacc[qc], 0, 0, 0);
        __builtin_amdgcn_s_setprio(0);

        // prefetch next K/V tile (coalesced 1KB wave-loads)
        const int kvn = (t + 1) & 63;
#pragma unroll
        for (int ks = 0; ks < 4; ++ks)
            kfp[ks] = *(const short8*)(kpb + ((size_t)kvn * 4 + ks) * 512 + lane * 8);
#pragma unroll
        for (int dt = 0; dt < 2; ++dt)
#pragma unroll
            for (int kb = 0; kb < 2; ++kb)
                vfp[dt * 2 + kb] = *(const short8*)(vpb + (((size_t)kvn * 2 + dt) * 2 + kb) *
                                                    512 + lane * 8);

#pragma unroll
        for (int qc = 0; qc < 2; ++qc) {
            // fixed-base softmax: P = exp2(s), per-lane partial sum
            float p[16];
#pragma unroll
            for (int r = 0; r < 16; ++r) p[r] = __builtin_amdgcn_exp2f(sacc[qc][r]);
            float s01 = (p[0] + p[1]) + (p[2] + p[3]);
            float s23 = (p[4] + p[5]) + (p[6] + p[7]);
            float s45 = (p[8] + p[9]) + (p[10] + p[11]);
            float s67 = (p[12] + p[13]) + (p[14] + p[15]);
            srun[qc] += (s01 + s23) + (s45 + s67);

            unsigned pk[4][2];
#pragma unroll
            for (int r1 = 0; r1 < 4; ++r1)
#pragma unroll
                for (int c = 0; c < 2; ++c)
                    asm("v_cvt_pk_bf16_f32 %0, %1, %2"
                        : "=v"(pk[r1][c])
                        : "v"(p[4 * r1 + 2 * c]), "v"(p[4 * r1 + 2 * c + 1]));

            short8 pb[2];
#pragma unroll
            for (int kb = 0; kb < 2; ++kb) {
                unsigned a0 = pk[2 * kb][0], b0 = pk[2 * kb + 1][0];
                unsigned a1 = pk[2 * kb][1], b1 = pk[2 * kb + 1][1];
                asm("v_permlane32_swap_b32 %0, %1" : "+v"(a0), "+v"(b0));
                asm("v_permlane32_swap_b32 %0, %1" : "+v"(a1), "+v"(b1));
                uint4v w;
                w[0] = a0; w[1] = a1; w[2] = b0; w[3] = b1;
                pb[kb] = __builtin_bit_cast(short8, w);
            }

            __builtin_amdgcn_s_setprio(1);
#pragma unroll
            for (int dt = 0; dt < 2; ++dt)
#pragma unroll
                for (int kb = 0; kb < 2; ++kb)
                    oacc[qc][dt] = __builtin_amdgcn_mfma_f32_32x32x16_bf16(
                        vfu[dt * 2 + kb], pb[kb], oacc[qc][dt], 0, 0, 0);
            __builtin_amdgcn_s_setprio(0);
        }
    };

    for (int t2 = 0; t2 < 64; t2 += 2) {
        iter(kfA, kfB, vfA, vfB, t2);
        iter(kfB, kfA, vfB, vfA, t2 + 1);
    }

    const int b = bh >> 4, h = bh & 15;
#pragma unroll
    for (int qc = 0; qc < 2; ++qc) {
        float s = srun[qc];
        s += __shfl_xor(s, 32, 64);
        const float inv = 1.f / s;
        const int qg = (qblk0 + qc) * 32 + lc;
        ushort_t* orow = Ov + (size_t)(b * N_ + qg) * C_ + h * HD_;
#pragma unroll
        for (int dt = 0; dt < 2; ++dt)
#pragma unroll
            for (int r1 = 0; r1 < 4; ++r1) {
                ushortx4 pkv;
#pragma unroll
                for (int r0 = 0; r0 < 4; ++r0)
                    pkv[r0] = f2bf(oacc[qc][dt][4 * r1 + r0] * inv);
                *(ushortx4*)(orow + dt * 32 + r1 * 8 + lh * 4) = pkv;
            }
    }
}

extern "C" void kernel_launch(void* const* d_in, const int* in_sizes, int n_in,
                              void* d_out, int out_size, void* d_ws, size_t ws_size,
                              hipStream_t stream) {
    const float* x = (const float*)d_in[0];
    const float* wqkv = (const float*)d_in[1];
    const float* wout = (const float*)d_in[2];
    const float* bout = (const float*)d_in[3];
    float* out = (float*)d_out;

    ushort_t* ws = (ushort_t*)d_ws;
    const size_t XN = (size_t)M_TOT * C_;       // 8388608
    const size_t WQN = (size_t)N3_ * C_;        // 3145728
    const size_t WON = (size_t)C_ * C_;         // 1048576
    ushort_t* xbf = ws;                         // also reused as vhat after gemm1
    ushort_t* wqkvb = xbf + XN;
    ushort_t* woutb = wqkvb + WQN;
    ushort_t* karr = woutb + WON;
    ushort_t* varr = karr + XN;
    ushort_t* qarr = varr + XN;
    ushort_t* vhat = xbf;  // alias: x_bf dead after gemm1

    cast_f32_bf16<<<2048, 256, 0, stream>>>(x, xbf, (int)(XN / 4));
    cast_f32_bf16<<<1024, 256, 0, stream>>>(wqkv, wqkvb, (int)(WQN / 4));
    cast_f32_bf16<<<512, 256, 0, stream>>>(wout, woutb, (int)(WON / 4));

    gemm_bt<0><<<dim3(24, 64), 256, 0, stream>>>(xbf, wqkvb, qarr, karr, varr,
                                                 nullptr, nullptr, C_);
    attn_fwd<<<512, 256, 0, stream>>>(qarr, karr, varr, vhat);
    gemm_bt<1><<<dim3(8, 64), 256, 0, stream>>>(vhat, woutb, nullptr, nullptr, nullptr,
                                                out, bout, C_);
}

// Round 11
// 180.083 us; speedup vs baseline: 1.1253x; 1.0771x over previous
//
#include <hip/hip_runtime.h>

typedef unsigned short ushort_t;
typedef __attribute__((ext_vector_type(8))) short short8;
typedef __attribute__((ext_vector_type(4))) float f32x4;
typedef __attribute__((ext_vector_type(16))) float f32x16;
typedef __attribute__((ext_vector_type(4))) float float4v;
typedef __attribute__((ext_vector_type(4))) unsigned short ushortx4;
typedef __attribute__((ext_vector_type(4))) unsigned int uint4v;

#define AS1 __attribute__((address_space(1)))
#define AS3 __attribute__((address_space(3)))

#define B_ 4
#define N_ 2048
#define C_ 1024
#define H_ 16
#define HD_ 64
#define M_TOT 8192
#define N3_ 3072

// q scale: 1/sqrt(64) * log2(e) so softmax runs in exp2 domain
#define QSCALE 0.18033688011112042f

__device__ __forceinline__ unsigned short f2bf(float f) {
    unsigned int u = __float_as_uint(f);
    u += 0x7fffu + ((u >> 16) & 1u);
    return (unsigned short)(u >> 16);
}

__global__ __launch_bounds__(256) void cast_f32_bf16(const float* __restrict__ in,
                                                     ushort_t* __restrict__ out, int n4) {
    int i = blockIdx.x * blockDim.x + threadIdx.x;
    int stride = gridDim.x * blockDim.x;
    for (; i < n4; i += stride) {
        float4v v = ((const float4v*)in)[i];
        ushortx4 o;
        o[0] = f2bf(v[0]); o[1] = f2bf(v[1]); o[2] = f2bf(v[2]); o[3] = f2bf(v[3]);
        ((ushortx4*)out)[i] = o;
    }
}

// ---------------------------------------------------------------------------
// gemm8p: C = A @ B^T pipelined GEMM. BM=256, BN=128, BK=64. 512 threads =
// 8 waves (4M x 2N), per-wave 64x64 output (acc[4][4] f32x4).
// K-tile split in two 32-wide k-slabs (kh); per tile: 2 phases (one per slab),
// 16 MFMA each. 2 LDS buffers x 48KB (dynamic, 96KB): stages for tile t+1 go
// to the idle buffer with counted s_waitcnt vmcnt(2) once per tile (never a
// full drain in steady state), 2 raw s_barriers per tile.
// LDS bank swizzle: slot ^= (row>>1)&3 (16B slots in 64B rows) -> 2-way (free).
// Applied via pre-swizzled GLOBAL source + linear global_load_lds dest.
// EPI 0: scatter qkv into fragment-major q (*QSCALE), k, v.  EPI 1: f32 + bias.
// ---------------------------------------------------------------------------
template <int EPI>
__global__ __launch_bounds__(512, 2) void gemm8p(const ushort_t* __restrict__ A,
                                                 const ushort_t* __restrict__ Bw,
                                                 ushort_t* __restrict__ o0,
                                                 ushort_t* __restrict__ o1,
                                                 ushort_t* __restrict__ o2,
                                                 float* __restrict__ outf,
                                                 const float* __restrict__ bias,
                                                 int K, int NBX) {
    extern __shared__ ushort_t smem[];  // 2 * 24576 elems (96 KB)
    const int tid = threadIdx.x;
    const int lane = tid & 63;
    const int wid = tid >> 6;
    const int l15 = lane & 15, lg = lane >> 4;
    const int wr = wid >> 1;        // 0..3 (M)
    const int wc = wid & 1;         // 0..1 (N)

    // XCD-bijective swizzle (gridDim.x % 8 == 0 for both gemms)
    const int wg = blockIdx.x;
    const int id = (wg & 7) * ((int)gridDim.x >> 3) + (wg >> 3);
    const int by = id / NBX, bx = id - by * NBX;
    const int m0 = by * 256, n0 = bx * 128;

    // read-side swizzle: logical k-slot g lives at dest slot g ^ ((row>>1)&3)
    const int koff = (((lane >> 4) ^ ((lane >> 1) & 3)) << 3);  // elems
    // stage-side: dest slot tid&3 holds logical slot (tid&3) ^ ((row>>1)&3)
    const int trow = tid >> 2;                        // 0..127
    const int slotsrc = (tid & 3) ^ ((tid >> 3) & 3);

    auto stageA = [&](int q, int tt, int kh, int c) {
        const ushort_t* src = A + (size_t)(m0 + c * 128 + trow) * K + tt * 64 + kh * 32 +
                              slotsrc * 8;
        ushort_t* dst = smem + q * 24576 + kh * 8192 + c * 4096 + tid * 8;
        __builtin_amdgcn_global_load_lds((const AS1 void*)src, (AS3 void*)dst, 16, 0, 0);
    };
    auto stageB = [&](int q, int tt, int kh) {
        const ushort_t* src = Bw + (size_t)(n0 + trow) * K + tt * 64 + kh * 32 + slotsrc * 8;
        ushort_t* dst = smem + q * 24576 + 16384 + kh * 4096 + tid * 8;
        __builtin_amdgcn_global_load_lds((const AS1 void*)src, (AS3 void*)dst, 16, 0, 0);
    };

    f32x4 acc[4][4] = {};

    auto phase = [&](int p, int kh) {
        const ushort_t* Ab = smem + p * 24576 + kh * 8192;
        const ushort_t* Bb = smem + p * 24576 + 16384 + kh * 4096;
        short8 af[4], bfr[4];
#pragma unroll
        for (int rt = 0; rt < 4; ++rt)
            af[rt] = *(const short8*)(Ab + (wr * 64 + rt * 16 + l15) * 32 + koff);
#pragma unroll
        for (int ni = 0; ni < 4; ++ni)
            bfr[ni] = *(const short8*)(Bb + (wc * 64 + ni * 16 + l15) * 32 + koff);
        __builtin_amdgcn_s_setprio(1);
#pragma unroll
        for (int rt = 0; rt < 4; ++rt)
#pragma unroll
            for (int ni = 0; ni < 4; ++ni)
                acc[rt][ni] = __builtin_amdgcn_mfma_f32_16x16x32_bf16(af[rt], bfr[ni],
                                                                      acc[rt][ni], 0, 0, 0);
        __builtin_amdgcn_s_setprio(0);
    };

    // prologue: full tile 0 into buf 0
    stageA(0, 0, 0, 0); stageA(0, 0, 0, 1);
    stageA(0, 0, 1, 0); stageA(0, 0, 1, 1);
    stageB(0, 0, 0);    stageB(0, 0, 1);

    const int NT = K >> 6;
    for (int t = 0; t < NT; ++t) {
        const int p = t & 1, q = p ^ 1;
        if (t + 1 < NT) {
            stageA(q, t + 1, 0, 0); stageA(q, t + 1, 0, 1);
            __builtin_amdgcn_sched_barrier(0);
            asm volatile("s_waitcnt vmcnt(2)");
        } else {
            asm volatile("s_waitcnt vmcnt(0)");
        }
        __builtin_amdgcn_sched_barrier(0);
        __builtin_amdgcn_s_barrier();          // B1: tile t fully staged, buf q free
        __builtin_amdgcn_sched_barrier(0);
        phase(p, 0);
        if (t + 1 < NT) {
            stageA(q, t + 1, 1, 0); stageA(q, t + 1, 1, 1);
            stageB(q, t + 1, 0);    stageB(q, t + 1, 1);
        }
        __builtin_amdgcn_sched_barrier(0);
        __builtin_amdgcn_s_barrier();          // B2: kh0 readers done before reuse window
        __builtin_amdgcn_sched_barrier(0);
        phase(p, 1);
    }

    if (EPI == 0) {
        const int sel = bx >> 3;  // 0=q 1=k 2=v, uniform per block (128-col blocks)
#pragma unroll
        for (int mi = 0; mi < 4; ++mi) {
            const int r0 = m0 + wr * 64 + mi * 16 + lg * 4;
            const int b = r0 >> 11, n = r0 & 2047;
            const int blk = n >> 5, nlo = n & 31;
#pragma unroll
            for (int ni = 0; ni < 4; ++ni) {
                const int cq = (bx & 7) * 128 + wc * 64 + ni * 16 + l15;
                const int h = cq >> 6, hd = cq & 63;
                const int bh = b * H_ + h;
                f32x4 a = acc[mi][ni];
                if (sel == 2) {
                    size_t base = (((size_t)(bh * 64 + blk) * 2 + (hd >> 5)) * 2 +
                                   ((n >> 4) & 1)) * 512 +
                                  ((hd & 31) + ((n >> 3) & 1) * 32) * 8 + (n & 7);
                    ushortx4 pk;
#pragma unroll
                    for (int j = 0; j < 4; ++j) pk[j] = f2bf(a[j]);
                    *(ushortx4*)(&o2[base]) = pk;
                } else {
                    size_t base = ((size_t)(bh * 64 + blk) * 4 + (hd >> 4)) * 512 +
                                  (nlo + ((hd >> 3) & 1) * 32) * 8 + (hd & 7);
                    if (sel == 0) {
#pragma unroll
                        for (int j = 0; j < 4; ++j) o0[base + j * 8] = f2bf(a[j] * QSCALE);
                    } else {
#pragma unroll
                        for (int j = 0; j < 4; ++j) o1[base + j * 8] = f2bf(a[j]);
                    }
                }
            }
        }
    } else {
#pragma unroll
        for (int ni = 0; ni < 4; ++ni) {
            const int c = n0 + wc * 64 + ni * 16 + l15;
            const float bv = bias[c];
#pragma unroll
            for (int mi = 0; mi < 4; ++mi) {
                const int r0 = m0 + wr * 64 + mi * 16 + lg * 4;
                f32x4 a = acc[mi][ni];
#pragma unroll
                for (int j = 0; j < 4; ++j)
                    outf[(size_t)(r0 + j) * C_ + c] = a[j] + bv;
            }
        }
    }
}

// Flash attention (round-4 best, 79.9us): fragment-major coalesced loads,
// 32x32x16 MFMA, fixed-base softmax, in-register P redistribution
// (cvt_pk_bf16 + permlane32_swap). 512 blocks XCD-swizzled, 4 waves x
// 64 q-rows, K/V register-pipelined one tile ahead.
__global__ __launch_bounds__(256, 2) void attn_fwd(const ushort_t* __restrict__ Qf,
                                                   const ushort_t* __restrict__ Kf,
                                                   const ushort_t* __restrict__ Vf,
                                                   ushort_t* __restrict__ Ov) {
    const int tid = threadIdx.x;
    const int lane = tid & 63;
    const int wid = tid >> 6;
    const int lc = lane & 31, lh = lane >> 5;

    const int wg = blockIdx.x;          // 512 blocks
    const int xcd = wg & 7, slot = wg >> 3;
    const int bh = xcd * 8 + (slot >> 3);
    const int qt = slot & 7;            // 8 q-chunks of 256 rows per bh

    const ushort_t* qpb = Qf + (size_t)bh * N_ * HD_;
    const ushort_t* kpb = Kf + (size_t)bh * N_ * HD_;
    const ushort_t* vpb = Vf + (size_t)bh * N_ * HD_;

    const int qblk0 = qt * 8 + wid * 2;

    short8 qf[2][4];
#pragma unroll
    for (int qc = 0; qc < 2; ++qc)
#pragma unroll
        for (int ks = 0; ks < 4; ++ks)
            qf[qc][ks] = *(const short8*)(qpb + ((size_t)(qblk0 + qc) * 4 + ks) * 512 +
                                          lane * 8);

    f32x16 oacc[2][2] = {};
    float srun[2] = {0.f, 0.f};

    short8 kfA[4], kfB[4], vfA[4], vfB[4];
#pragma unroll
    for (int ks = 0; ks < 4; ++ks)
        kfA[ks] = *(const short8*)(kpb + (size_t)ks * 512 + lane * 8);
#pragma unroll
    for (int dt = 0; dt < 2; ++dt)
#pragma unroll
        for (int kb = 0; kb < 2; ++kb)
            vfA[dt * 2 + kb] = *(const short8*)(vpb + ((size_t)dt * 2 + kb) * 512 + lane * 8);

    auto iter = [&](short8(&kfu)[4], short8(&kfp)[4], short8(&vfu)[4], short8(&vfp)[4],
                    int t) {
        f32x16 sacc[2] = {};
        __builtin_amdgcn_s_setprio(1);
#pragma unroll
        for (int ks = 0; ks < 4; ++ks)
#pragma unroll
            for (int qc = 0; qc < 2; ++qc)
                sacc[qc] = __builtin_amdgcn_mfma_f32_32x32x16_bf16(kfu[ks], qf[qc][ks],
                                                                   sacc[qc], 0, 0, 0);
        __builtin_amdgcn_s_setprio(0);

        const int kvn = (t + 1) & 63;
#pragma unroll
        for (int ks = 0; ks < 4; ++ks)
            kfp[ks] = *(const short8*)(kpb + ((size_t)kvn * 4 + ks) * 512 + lane * 8);
#pragma unroll
        for (int dt = 0; dt < 2; ++dt)
#pragma unroll
            for (int kb = 0; kb < 2; ++kb)
                vfp[dt * 2 + kb] = *(const short8*)(vpb + (((size_t)kvn * 2 + dt) * 2 + kb) *
                                                    512 + lane * 8);

#pragma unroll
        for (int qc = 0; qc < 2; ++qc) {
            float p[16];
#pragma unroll
            for (int r = 0; r < 16; ++r) p[r] = __builtin_amdgcn_exp2f(sacc[qc][r]);
            float s01 = (p[0] + p[1]) + (p[2] + p[3]);
            float s23 = (p[4] + p[5]) + (p[6] + p[7]);
            float s45 = (p[8] + p[9]) + (p[10] + p[11]);
            float s67 = (p[12] + p[13]) + (p[14] + p[15]);
            srun[qc] += (s01 + s23) + (s45 + s67);

            unsigned pk[4][2];
#pragma unroll
            for (int r1 = 0; r1 < 4; ++r1)
#pragma unroll
                for (int c = 0; c < 2; ++c)
                    asm("v_cvt_pk_bf16_f32 %0, %1, %2"
                        : "=v"(pk[r1][c])
                        : "v"(p[4 * r1 + 2 * c]), "v"(p[4 * r1 + 2 * c + 1]));

            short8 pb[2];
#pragma unroll
            for (int kb = 0; kb < 2; ++kb) {
                unsigned a0 = pk[2 * kb][0], b0 = pk[2 * kb + 1][0];
                unsigned a1 = pk[2 * kb][1], b1 = pk[2 * kb + 1][1];
                asm("v_permlane32_swap_b32 %0, %1" : "+v"(a0), "+v"(b0));
                asm("v_permlane32_swap_b32 %0, %1" : "+v"(a1), "+v"(b1));
                uint4v w;
                w[0] = a0; w[1] = a1; w[2] = b0; w[3] = b1;
                pb[kb] = __builtin_bit_cast(short8, w);
            }

            __builtin_amdgcn_s_setprio(1);
#pragma unroll
            for (int dt = 0; dt < 2; ++dt)
#pragma unroll
                for (int kb = 0; kb < 2; ++kb)
                    oacc[qc][dt] = __builtin_amdgcn_mfma_f32_32x32x16_bf16(
                        vfu[dt * 2 + kb], pb[kb], oacc[qc][dt], 0, 0, 0);
            __builtin_amdgcn_s_setprio(0);
        }
    };

    for (int t2 = 0; t2 < 64; t2 += 2) {
        iter(kfA, kfB, vfA, vfB, t2);
        iter(kfB, kfA, vfB, vfA, t2 + 1);
    }

    const int b = bh >> 4, h = bh & 15;
#pragma unroll
    for (int qc = 0; qc < 2; ++qc) {
        float s = srun[qc];
        s += __shfl_xor(s, 32, 64);
        const float inv = 1.f / s;
        const int qg = (qblk0 + qc) * 32 + lc;
        ushort_t* orow = Ov + (size_t)(b * N_ + qg) * C_ + h * HD_;
#pragma unroll
        for (int dt = 0; dt < 2; ++dt)
#pragma unroll
            for (int r1 = 0; r1 < 4; ++r1) {
                ushortx4 pkv;
#pragma unroll
                for (int r0 = 0; r0 < 4; ++r0)
                    pkv[r0] = f2bf(oacc[qc][dt][4 * r1 + r0] * inv);
                *(ushortx4*)(orow + dt * 32 + r1 * 8 + lh * 4) = pkv;
            }
    }
}

extern "C" void kernel_launch(void* const* d_in, const int* in_sizes, int n_in,
                              void* d_out, int out_size, void* d_ws, size_t ws_size,
                              hipStream_t stream) {
    const float* x = (const float*)d_in[0];
    const float* wqkv = (const float*)d_in[1];
    const float* wout = (const float*)d_in[2];
    const float* bout = (const float*)d_in[3];
    float* out = (float*)d_out;

    ushort_t* ws = (ushort_t*)d_ws;
    const size_t XN = (size_t)M_TOT * C_;       // 8388608
    const size_t WQN = (size_t)N3_ * C_;        // 3145728
    const size_t WON = (size_t)C_ * C_;         // 1048576
    ushort_t* xbf = ws;                         // also reused as vhat after gemm1
    ushort_t* wqkvb = xbf + XN;
    ushort_t* woutb = wqkvb + WQN;
    ushort_t* karr = woutb + WON;
    ushort_t* varr = karr + XN;
    ushort_t* qarr = varr + XN;
    ushort_t* vhat = xbf;  // alias: x_bf dead after gemm1

    cast_f32_bf16<<<2048, 256, 0, stream>>>(x, xbf, (int)(XN / 4));
    cast_f32_bf16<<<1024, 256, 0, stream>>>(wqkv, wqkvb, (int)(WQN / 4));
    cast_f32_bf16<<<512, 256, 0, stream>>>(wout, woutb, (int)(WON / 4));

    gemm8p<0><<<768, 512, 98304, stream>>>(xbf, wqkvb, qarr, karr, varr,
                                           nullptr, nullptr, C_, 24);
    attn_fwd<<<512, 256, 0, stream>>>(qarr, karr, varr, vhat);
    gemm8p<1><<<256, 512, 98304, stream>>>(vhat, woutb, nullptr, nullptr, nullptr,
                                           out, bout, C_, 8);
}